// Round 6
// baseline (155.963 us; speedup 1.0000x reference)
//
#include <hip/hip_runtime.h>
#include <hip/hip_bf16.h>
#include <stdint.h>

// B=8192 triplet loss with hard-negative mining.
// prep: normalize -> bf16
// dist_topk: K-accumulating GEMM tiles (128x256 per block, 8 waves of 64x64),
//            1-step prefetch, mining ONCE per block in the epilogue via
//            positive-float packed keys + v_max/v_med3 insert.
// merge_loss: merge 32 sorted runs, JAX threefry RNG, exact fp32 loss per row
// finalize: deterministic mean

#define NB 8192
#define NCG 32        // col-groups of 256
#define EPSF 1e-6f

typedef float f32x4 __attribute__((ext_vector_type(4)));
typedef short short8 __attribute__((ext_vector_type(8)));

struct U2 { uint32_t x, y; };

__host__ __device__ __forceinline__ uint32_t rotl32(uint32_t v, int n) {
  return (v << n) | (v >> (32 - n));
}

__host__ __device__ __forceinline__ U2 tf2x32(uint32_t k0, uint32_t k1,
                                              uint32_t x0, uint32_t x1) {
  uint32_t k2 = k0 ^ k1 ^ 0x1BD11BDAu;
#define TF_R(r) { x0 += x1; x1 = rotl32(x1, r); x1 ^= x0; }
  x0 += k0; x1 += k1;
  TF_R(13) TF_R(15) TF_R(26) TF_R(6)
  x0 += k1; x1 += k2 + 1u;
  TF_R(17) TF_R(29) TF_R(16) TF_R(24)
  x0 += k2; x1 += k0 + 2u;
  TF_R(13) TF_R(15) TF_R(26) TF_R(6)
  x0 += k0; x1 += k1 + 3u;
  TF_R(17) TF_R(29) TF_R(16) TF_R(24)
  x0 += k1; x1 += k2 + 4u;
  TF_R(13) TF_R(15) TF_R(26) TF_R(6)
  x0 += k2; x1 += k0 + 5u;
#undef TF_R
  U2 r; r.x = x0; r.y = x1; return r;
}

__device__ __forceinline__ uint32_t rng_word(U2 r) { return r.x ^ r.y; }

// float insertion into sorted-desc top-5 (keys are positive floats, so
// float order == u32 order); 5 independent ops.
#define FINS5(T0, T1, T2, T3, T4, C) {            \
    const float _t0 = T0, _t1 = T1, _t2 = T2, _t3 = T3, _t4 = T4, _c = C; \
    T0 = fmaxf(_t0, _c);                          \
    T1 = __builtin_amdgcn_fmed3f(_c, _t0, _t1);   \
    T2 = __builtin_amdgcn_fmed3f(_c, _t1, _t2);   \
    T3 = __builtin_amdgcn_fmed3f(_c, _t2, _t3);   \
    T4 = __builtin_amdgcn_fmed3f(_c, _t3, _t4); }

// ---------------- prep: normalize -> bf16 ----------------
__global__ __launch_bounds__(256) void prep_kernel(
    const float* __restrict__ x,
    __hip_bfloat16* __restrict__ abf, __hip_bfloat16* __restrict__ pbf) {
  const int w = threadIdx.x >> 6, l = threadIdx.x & 63;
  const int row = blockIdx.x * 4 + w;
  const float4* xr = (const float4*)(x + (size_t)row * 512);
  const float4 a4 = xr[l];
  const float4 p4 = xr[64 + l];
  float sa = a4.x * a4.x + a4.y * a4.y + a4.z * a4.z + a4.w * a4.w;
  float sp = p4.x * p4.x + p4.y * p4.y + p4.z * p4.z + p4.w * p4.w;
#pragma unroll
  for (int off = 32; off; off >>= 1) { sa += __shfl_xor(sa, off); sp += __shfl_xor(sp, off); }
  const float ia = 1.0f / fmaxf(sqrtf(sa), 1e-12f);
  const float ip_ = 1.0f / fmaxf(sqrtf(sp), 1e-12f);
  ushort4 ua, up;
  ua.x = __builtin_bit_cast(unsigned short, __float2bfloat16(a4.x * ia));
  ua.y = __builtin_bit_cast(unsigned short, __float2bfloat16(a4.y * ia));
  ua.z = __builtin_bit_cast(unsigned short, __float2bfloat16(a4.z * ia));
  ua.w = __builtin_bit_cast(unsigned short, __float2bfloat16(a4.w * ia));
  up.x = __builtin_bit_cast(unsigned short, __float2bfloat16(p4.x * ip_));
  up.y = __builtin_bit_cast(unsigned short, __float2bfloat16(p4.y * ip_));
  up.z = __builtin_bit_cast(unsigned short, __float2bfloat16(p4.z * ip_));
  up.w = __builtin_bit_cast(unsigned short, __float2bfloat16(p4.w * ip_));
  *(ushort4*)((char*)abf + (size_t)row * 512 + l * 8) = ua;
  *(ushort4*)((char*)pbf + (size_t)row * 512 + l * 8) = up;
}

// ---------------- dist + per-row top-5 ----------------
// grid: 2048 blocks (64 rb x 32 cb, XCD-supertile swizzled), 512 thr = 8 waves
// in 2x4: wave (wr,wcq) owns a-rows [rb*128+wr*64,+64) x p-cols
// [cb*256+wcq*64,+64). K-loop 8 steps of 32, acc[4][4] accumulates; mining
// once in the epilogue. mfma(bF, aF): a-row (C col) = wrow+aq*16+lo,
// p-col (C row) = wcol+pq*16+hi*4+r.
__global__ __launch_bounds__(512, 2) void dist_topk_kernel(
    const __hip_bfloat16* __restrict__ abf, const __hip_bfloat16* __restrict__ pbf,
    uint32_t* __restrict__ part) {
  __shared__ uint32_t mls[2][5120]; // [wr][row_local*80 + wcq*20 + hi*5 + q]

  const int tid = threadIdx.x;
  const int w = tid >> 6, l = tid & 63;
  const int lo = l & 15, hi = l >> 4;
  const int wr = w >> 2, wcq = w & 3;

  // XCD supertile swizzle: 8 supertiles of 16x16 blocks; xcd = b&7.
  // Per XCD: A 2048 rows (1MB) + B 4096 cols (2MB) < 4MB L2.
  const int b = blockIdx.x;
  const int xcd = b & 7, j = b >> 3;          // j: 0..255
  const int rb = (xcd >> 1) * 16 + (j >> 4);  // 0..63 (128 rows)
  const int cb = (xcd & 1) * 16 + (j & 15);   // 0..31 (256 cols)

  const int wrow = rb * 128 + wr * 64;
  const int wcol = cb * 256 + wcq * 64;
  const bool hasDiag = ((wrow >> 6) == (wcol >> 6));

  const char* aP = (const char*)abf + (size_t)(wrow + lo) * 512 + hi * 16;
  const char* bP = (const char*)pbf + (size_t)(wcol + lo) * 512 + hi * 16;

  f32x4 acc[4][4];
#pragma unroll
  for (int aq = 0; aq < 4; ++aq)
#pragma unroll
    for (int pq = 0; pq < 4; ++pq) { f32x4 z = {0.f, 0.f, 0.f, 0.f}; acc[aq][pq] = z; }

  short8 a0[4], b0[4], a1[4], b1[4];

#define LOADF(AX, BX, S)                                                    \
  {                                                                         \
    _Pragma("unroll")                                                       \
    for (int q = 0; q < 4; ++q) {                                           \
      AX[q] = *(const short8*)(aP + q * 8192 + (S) * 64);                   \
      BX[q] = *(const short8*)(bP + q * 8192 + (S) * 64);                   \
    }                                                                       \
  }

#define MFMAS(AX, BX)                                                       \
  {                                                                         \
    _Pragma("unroll")                                                       \
    for (int aq = 0; aq < 4; ++aq)                                          \
      _Pragma("unroll")                                                     \
      for (int pq = 0; pq < 4; ++pq)                                        \
        acc[aq][pq] = __builtin_amdgcn_mfma_f32_16x16x32_bf16(              \
            BX[pq], AX[aq], acc[aq][pq], 0, 0, 0);                          \
  }

  LOADF(a0, b0, 0)
  LOADF(a1, b1, 1) MFMAS(a0, b0)
  LOADF(a0, b0, 2) MFMAS(a1, b1)
  LOADF(a1, b1, 3) MFMAS(a0, b0)
  LOADF(a0, b0, 4) MFMAS(a1, b1)
  LOADF(a1, b1, 5) MFMAS(a0, b0)
  LOADF(a0, b0, 6) MFMAS(a1, b1)
  LOADF(a1, b1, 7) MFMAS(a0, b0)
  MFMAS(a1, b1)

#undef LOADF
#undef MFMAS

  // epilogue mine: per aq (a-row = wrow+aq*16+lo), 16 candidates
  const uint32_t vbase = 8191u - (uint32_t)wcol - (uint32_t)(hi * 4);
#pragma unroll
  for (int aq = 0; aq < 4; ++aq) {
    float T0 = 0.f, T1 = 0.f, T2 = 0.f, T3 = 0.f, T4 = 0.f;
    const int arow = wrow + aq * 16 + lo;
#pragma unroll
    for (int pq = 0; pq < 4; ++pq)
#pragma unroll
      for (int r = 0; r < 4; ++r) {
        uint32_t key = (__float_as_uint(acc[aq][pq][r] + 2.0f) & 0xFFFFE000u) |
                       (vbase - (uint32_t)(pq * 16 + r));
        if (hasDiag) {
          if (wcol + pq * 16 + hi * 4 + r == arow) key = 0u;
        }
        const float c = __uint_as_float(key);
        FINS5(T0, T1, T2, T3, T4, c);
      }
    const int base = (aq * 16 + lo) * 80 + wcq * 20 + hi * 5;
    mls[wr][base + 0] = __float_as_uint(T0);
    mls[wr][base + 1] = __float_as_uint(T1);
    mls[wr][base + 2] = __float_as_uint(T2);
    mls[wr][base + 3] = __float_as_uint(T3);
    mls[wr][base + 4] = __float_as_uint(T4);
  }
  __syncthreads();

  // block-level merge: 128 rows, threads 0..127 each merge 80 candidates
  if (tid < 128) {
    const int wrg = tid >> 6, rl = tid & 63;
    float M0 = 0.f, M1 = 0.f, M2 = 0.f, M3 = 0.f, M4 = 0.f;
    const uint32_t* src = &mls[wrg][rl * 80];
#pragma unroll 4
    for (int k = 0; k < 80; ++k) {
      const float c = __uint_as_float(src[k]);
      FINS5(M0, M1, M2, M3, M4, c);
    }
    const int row = rb * 128 + wrg * 64 + rl;
    uint32_t* dst = part + ((size_t)row * NCG + cb) * 5;
    dst[0] = __float_as_uint(M0);
    dst[1] = __float_as_uint(M1);
    dst[2] = __float_as_uint(M2);
    dst[3] = __float_as_uint(M3);
    dst[4] = __float_as_uint(M4);
  }
}

// ---------------- merge splits + RNG + exact fp32 loss ----------------
__global__ __launch_bounds__(64) void merge_loss_kernel(
    const float* __restrict__ x, const uint32_t* __restrict__ part,
    float* __restrict__ rowloss,
    uint32_t k1a, uint32_t k1b, uint32_t k2a, uint32_t k2b) {
  const int i = blockIdx.x, l = threadIdx.x;
  __shared__ uint32_t cs[NCG * 5];
  const uint32_t* src = part + (size_t)i * (NCG * 5);
  cs[l] = src[l];
  cs[64 + l] = src[64 + l];
  if (l < 32) cs[128 + l] = src[128 + l];
  __syncthreads();

  float T0 = 0.f, T1 = 0.f, T2 = 0.f, T3 = 0.f, T4 = 0.f;
  for (int rch = 0; rch < NCG; ++rch) {
    for (int q = 0; q < 5; ++q) {      // runs sorted desc -> early out (uniform)
      const float c = __uint_as_float(cs[rch * 5 + q]);
      if (c <= T4) break;
      FINS5(T0, T1, T2, T3, T4, c);
    }
  }

  // RNG: coin = uniform(k1) < 0.5 <=> MSB==0 ; randint(k2,0,5)
  const uint32_t cw = rng_word(tf2x32(k1a, k1b, 0u, (uint32_t)i));
  const bool coin = (cw >> 31) == 0u;
  const uint32_t hb = rng_word(tf2x32(k2a, k2b, 0u, (uint32_t)i));
  const uint32_t lb = rng_word(tf2x32(k2a, k2b, 0u, (uint32_t)(NB + i)));
  const int rr = (int)(((hb % 5u) + (lb % 5u)) % 5u);
  const int rank = coin ? 0 : rr;
  const float kch = (rank == 0) ? T0 : (rank == 1) ? T1 : (rank == 2) ? T2
                  : (rank == 3) ? T3 : T4;
  const int neg = 8191 - (int)(__float_as_uint(kch) & 8191u);

  // exact fp32 loss from raw x
  const float4 xa = *(const float4*)(x + (size_t)i * 512 + l * 4);
  const float4 xp = *(const float4*)(x + (size_t)i * 512 + 256 + l * 4);
  const float4 xn = *(const float4*)(x + (size_t)neg * 512 + 256 + l * 4);
  float sa = xa.x * xa.x + xa.y * xa.y + xa.z * xa.z + xa.w * xa.w;
  float sp = xp.x * xp.x + xp.y * xp.y + xp.z * xp.z + xp.w * xp.w;
  float sn = xn.x * xn.x + xn.y * xn.y + xn.z * xn.z + xn.w * xn.w;
#pragma unroll
  for (int off = 32; off; off >>= 1) {
    sa += __shfl_xor(sa, off); sp += __shfl_xor(sp, off); sn += __shfl_xor(sn, off);
  }
  const float na = fmaxf(sqrtf(sa), 1e-12f);
  const float np = fmaxf(sqrtf(sp), 1e-12f);
  const float nn = fmaxf(sqrtf(sn), 1e-12f);

  float pos = 0.f, ng = 0.f;
  {
    float av, pv, nv, dp, dn;
    av = xa.x / na; pv = xp.x / np; nv = xn.x / nn;
    dp = av - pv + EPSF; pos += dp * dp; dn = av - nv + EPSF; ng += dn * dn;
    av = xa.y / na; pv = xp.y / np; nv = xn.y / nn;
    dp = av - pv + EPSF; pos += dp * dp; dn = av - nv + EPSF; ng += dn * dn;
    av = xa.z / na; pv = xp.z / np; nv = xn.z / nn;
    dp = av - pv + EPSF; pos += dp * dp; dn = av - nv + EPSF; ng += dn * dn;
    av = xa.w / na; pv = xp.w / np; nv = xn.w / nn;
    dp = av - pv + EPSF; pos += dp * dp; dn = av - nv + EPSF; ng += dn * dn;
  }
#pragma unroll
  for (int off = 32; off; off >>= 1) {
    pos += __shfl_xor(pos, off); ng += __shfl_xor(ng, off);
  }
  if (l == 0) rowloss[i] = fmaxf(pos - ng, 0.0f);
}

// ---------------- deterministic mean ----------------
__global__ __launch_bounds__(256) void finalize_kernel(
    const float* __restrict__ rowloss, float* __restrict__ out) {
  __shared__ float s[256];
  const int t = threadIdx.x;
  float a = 0.f;
  for (int k = 0; k < NB / 256; ++k) a += rowloss[t + 256 * k];
  s[t] = a;
  __syncthreads();
  for (int h = 128; h; h >>= 1) {
    if (t < h) s[t] += s[t + h];
    __syncthreads();
  }
  if (t == 0) out[0] = s[0] / (float)NB;
}

extern "C" void kernel_launch(void* const* d_in, const int* in_sizes, int n_in,
                              void* d_out, int out_size, void* d_ws, size_t ws_size,
                              hipStream_t stream) {
  (void)in_sizes; (void)n_in; (void)out_size; (void)ws_size;
  const float* x = (const float*)d_in[0];
  float* out = (float*)d_out;
  char* ws = (char*)d_ws;

  __hip_bfloat16* abf = (__hip_bfloat16*)(ws);                            // 4 MB
  __hip_bfloat16* pbf = (__hip_bfloat16*)(ws + (size_t)4 * 1024 * 1024);  // 4 MB
  uint32_t* part = (uint32_t*)(ws + (size_t)8 * 1024 * 1024);             // 5.24 MB
  float* rowloss = (float*)(ws + (size_t)8 * 1024 * 1024 +
                            (size_t)NB * NCG * 5 * sizeof(uint32_t));     // 32 KB

  // JAX: kr = key(1); k1, k2 = split(kr)  (threefry partitionable)
  U2 c0 = tf2x32(0u, 1u, 0u, 0u);
  U2 c1 = tf2x32(0u, 1u, 0u, 1u);
  const uint32_t k1a = c0.x, k1b = c0.y;
  const uint32_t k2a = c1.x, k2b = c1.y;

  prep_kernel<<<NB / 4, 256, 0, stream>>>(x, abf, pbf);
  dist_topk_kernel<<<2048, 512, 0, stream>>>(abf, pbf, part);
  merge_loss_kernel<<<NB, 64, 0, stream>>>(x, part, rowloss, k1a, k1b, k2a, k2b);
  finalize_kernel<<<1, 256, 0, stream>>>(rowloss, out);
}

// Round 7
// 80.001 us; speedup vs baseline: 1.9495x; 1.9495x over previous
//
#include <hip/hip_runtime.h>
#include <hip/hip_bf16.h>
#include <stdint.h>

// B=8192 triplet loss with hard-negative mining.
// prep: normalize -> bf16
// dist_topk: m97-style LDS-staged GEMM. 128x256 tile, BK=64, 8 waves (2x4 of
//            64x64), single-buffer 48KB LDS via global_load_lds (width 16,
//            source-swizzled / read-swizzled XOR), 2-barrier K-loop,
//            epilogue mining with packed keys + v_max/v_med3 insert.
// merge_loss: merge 32 sorted runs (4 rows/block), JAX threefry RNG,
//             exact fp32 loss per row
// finalize: deterministic mean

#define NB 8192
#define NCG 32        // col-groups of 256
#define EPSF 1e-6f

typedef float f32x4 __attribute__((ext_vector_type(4)));
typedef short short8 __attribute__((ext_vector_type(8)));

struct U2 { uint32_t x, y; };

__host__ __device__ __forceinline__ uint32_t rotl32(uint32_t v, int n) {
  return (v << n) | (v >> (32 - n));
}

__host__ __device__ __forceinline__ U2 tf2x32(uint32_t k0, uint32_t k1,
                                              uint32_t x0, uint32_t x1) {
  uint32_t k2 = k0 ^ k1 ^ 0x1BD11BDAu;
#define TF_R(r) { x0 += x1; x1 = rotl32(x1, r); x1 ^= x0; }
  x0 += k0; x1 += k1;
  TF_R(13) TF_R(15) TF_R(26) TF_R(6)
  x0 += k1; x1 += k2 + 1u;
  TF_R(17) TF_R(29) TF_R(16) TF_R(24)
  x0 += k2; x1 += k0 + 2u;
  TF_R(13) TF_R(15) TF_R(26) TF_R(6)
  x0 += k0; x1 += k1 + 3u;
  TF_R(17) TF_R(29) TF_R(16) TF_R(24)
  x0 += k1; x1 += k2 + 4u;
  TF_R(13) TF_R(15) TF_R(26) TF_R(6)
  x0 += k2; x1 += k0 + 5u;
#undef TF_R
  U2 r; r.x = x0; r.y = x1; return r;
}

__device__ __forceinline__ uint32_t rng_word(U2 r) { return r.x ^ r.y; }

// float insertion into sorted-desc top-5 (keys are positive floats, so
// float order == u32 order); 5 independent ops.
#define FINS5(T0, T1, T2, T3, T4, C) {            \
    const float _t0 = T0, _t1 = T1, _t2 = T2, _t3 = T3, _t4 = T4, _c = C; \
    T0 = fmaxf(_t0, _c);                          \
    T1 = __builtin_amdgcn_fmed3f(_c, _t0, _t1);   \
    T2 = __builtin_amdgcn_fmed3f(_c, _t1, _t2);   \
    T3 = __builtin_amdgcn_fmed3f(_c, _t2, _t3);   \
    T4 = __builtin_amdgcn_fmed3f(_c, _t3, _t4); }

__device__ __forceinline__ void gload16(const void* g, void* l) {
  __builtin_amdgcn_global_load_lds(
      (const __attribute__((address_space(1))) unsigned int*)g,
      (__attribute__((address_space(3))) unsigned int*)l, 16, 0, 0);
}

// ---------------- prep: normalize -> bf16 ----------------
__global__ __launch_bounds__(256) void prep_kernel(
    const float* __restrict__ x,
    __hip_bfloat16* __restrict__ abf, __hip_bfloat16* __restrict__ pbf) {
  const int w = threadIdx.x >> 6, l = threadIdx.x & 63;
  const int row = blockIdx.x * 4 + w;
  const float4* xr = (const float4*)(x + (size_t)row * 512);
  const float4 a4 = xr[l];
  const float4 p4 = xr[64 + l];
  float sa = a4.x * a4.x + a4.y * a4.y + a4.z * a4.z + a4.w * a4.w;
  float sp = p4.x * p4.x + p4.y * p4.y + p4.z * p4.z + p4.w * p4.w;
#pragma unroll
  for (int off = 32; off; off >>= 1) { sa += __shfl_xor(sa, off); sp += __shfl_xor(sp, off); }
  const float ia = 1.0f / fmaxf(sqrtf(sa), 1e-12f);
  const float ip_ = 1.0f / fmaxf(sqrtf(sp), 1e-12f);
  ushort4 ua, up;
  ua.x = __builtin_bit_cast(unsigned short, __float2bfloat16(a4.x * ia));
  ua.y = __builtin_bit_cast(unsigned short, __float2bfloat16(a4.y * ia));
  ua.z = __builtin_bit_cast(unsigned short, __float2bfloat16(a4.z * ia));
  ua.w = __builtin_bit_cast(unsigned short, __float2bfloat16(a4.w * ia));
  up.x = __builtin_bit_cast(unsigned short, __float2bfloat16(p4.x * ip_));
  up.y = __builtin_bit_cast(unsigned short, __float2bfloat16(p4.y * ip_));
  up.z = __builtin_bit_cast(unsigned short, __float2bfloat16(p4.z * ip_));
  up.w = __builtin_bit_cast(unsigned short, __float2bfloat16(p4.w * ip_));
  *(ushort4*)((char*)abf + (size_t)row * 512 + l * 8) = ua;
  *(ushort4*)((char*)pbf + (size_t)row * 512 + l * 8) = up;
}

// ---------------- dist + per-row top-5 ----------------
// grid: 2048 blocks (64 rb x 32 cb, XCD supertile), 512 thr = 8 waves (2x4);
// wave (wr,wc) owns a-rows [rb*128+wr*64,+64) x p-cols [cb*256+wc*64,+64).
// LDS: A-tile 128x64 bf16 (16KB) + B-tile 256x64 (32KB), XOR-swizzled.
// mfma(bF, aF): a-row (C col) = row0+wr*64+aq*16+lo;
// p-col (C row) = col0+wc*64+pq*16+hi*4+r.
__global__ __launch_bounds__(512, 4) void dist_topk_kernel(
    const __hip_bfloat16* __restrict__ abf, const __hip_bfloat16* __restrict__ pbf,
    uint32_t* __restrict__ part) {
  __shared__ __align__(16) char smem[49152]; // A 16KB | B 32KB; reused as merge scratch

  const int tid = threadIdx.x;
  const int w = tid >> 6, l = tid & 63;
  const int lo = l & 15, hi = l >> 4;
  const int wr = w >> 2, wc = w & 3;

  // XCD supertile swizzle: per XCD 2048 rows (1MB A) + 4096 cols (2MB B) < 4MB L2
  const int b = blockIdx.x;
  const int xcd = b & 7, j = b >> 3;          // j: 0..255
  const int rb = (xcd >> 1) * 16 + (j >> 4);  // 0..63 (128 rows)
  const int cb = (xcd & 1) * 16 + (j & 15);   // 0..31 (256 cols)
  const int row0 = rb * 128, col0 = cb * 256;
  const bool hasDiag = (cb == (rb >> 1));

  f32x4 acc[4][4];
#pragma unroll
  for (int aq = 0; aq < 4; ++aq)
#pragma unroll
    for (int pq = 0; pq < 4; ++pq) { f32x4 z = {0.f, 0.f, 0.f, 0.f}; acc[aq][pq] = z; }

#pragma unroll 1
  for (int ks = 0; ks < 4; ++ks) {
    if (ks) __syncthreads();                  // readers done with buffer
    // stage A-tile: 2 insts x 8KB (linear LDS dest, source pre-swizzled)
#pragma unroll
    for (int jj = 0; jj < 2; ++jj) {
      const int off = jj * 8192 + tid * 16;
      const int r = off >> 7, kbs = off & 127;
      const int kb = kbs ^ ((r & 7) << 4);
      gload16((const char*)abf + (size_t)(row0 + r) * 512 + ks * 128 + kb, smem + off);
    }
    // stage B-tile: 4 insts x 8KB
#pragma unroll
    for (int jj = 0; jj < 4; ++jj) {
      const int off = jj * 8192 + tid * 16;
      const int r = off >> 7, kbs = off & 127;
      const int kb = kbs ^ ((r & 7) << 4);
      gload16((const char*)pbf + (size_t)(col0 + r) * 512 + ks * 128 + kb,
              smem + 16384 + off);
    }
    __syncthreads();                          // vmcnt(0) drain -> data visible

#pragma unroll
    for (int kk = 0; kk < 2; ++kk) {
      short8 aF[4], bF[4];
#pragma unroll
      for (int aq = 0; aq < 4; ++aq) {
        const int r = wr * 64 + aq * 16 + lo;
        aF[aq] = *(const short8*)(smem + r * 128 +
                                  ((kk * 64 + hi * 16) ^ ((r & 7) << 4)));
      }
#pragma unroll
      for (int pq = 0; pq < 4; ++pq) {
        const int c = wc * 64 + pq * 16 + lo;
        bF[pq] = *(const short8*)(smem + 16384 + c * 128 +
                                  ((kk * 64 + hi * 16) ^ ((c & 7) << 4)));
      }
#pragma unroll
      for (int aq = 0; aq < 4; ++aq)
#pragma unroll
        for (int pq = 0; pq < 4; ++pq)
          acc[aq][pq] = __builtin_amdgcn_mfma_f32_16x16x32_bf16(
              bF[pq], aF[aq], acc[aq][pq], 0, 0, 0);
    }
  }

  // epilogue mine: per aq (a-row), 16 candidates -> top-5 keys
  const uint32_t vbase = 8191u - (uint32_t)(col0 + wc * 64) - (uint32_t)(hi * 4);
  uint32_t tk[4][5];
#pragma unroll
  for (int aq = 0; aq < 4; ++aq) {
    float T0 = 0.f, T1 = 0.f, T2 = 0.f, T3 = 0.f, T4 = 0.f;
    const int arow = row0 + wr * 64 + aq * 16 + lo;
#pragma unroll
    for (int pq = 0; pq < 4; ++pq)
#pragma unroll
      for (int r = 0; r < 4; ++r) {
        uint32_t key = (__float_as_uint(acc[aq][pq][r] + 2.0f) & 0xFFFFE000u) |
                       (vbase - (uint32_t)(pq * 16 + r));
        if (hasDiag) {
          if (col0 + wc * 64 + pq * 16 + hi * 4 + r == arow) key = 0u;
        }
        const float c = __uint_as_float(key);
        FINS5(T0, T1, T2, T3, T4, c);
      }
    tk[aq][0] = __float_as_uint(T0); tk[aq][1] = __float_as_uint(T1);
    tk[aq][2] = __float_as_uint(T2); tk[aq][3] = __float_as_uint(T3);
    tk[aq][4] = __float_as_uint(T4);
  }

  __syncthreads();                            // tile reads done; reuse smem
  uint32_t* mls = (uint32_t*)smem;            // [wr][64 rows][81] stride-81 pad
#pragma unroll
  for (int aq = 0; aq < 4; ++aq) {
    const int base = wr * 5184 + (aq * 16 + lo) * 81 + wc * 20 + hi * 5;
#pragma unroll
    for (int q = 0; q < 5; ++q) mls[base + q] = tk[aq][q];
  }
  __syncthreads();

  // block-level merge: 128 rows, threads 0..127 each merge 80 candidates
  if (tid < 128) {
    const int wrg = tid >> 6, rloc = tid & 63;
    const uint32_t* s2 = mls + wrg * 5184 + rloc * 81;
    float M0 = 0.f, M1 = 0.f, M2 = 0.f, M3 = 0.f, M4 = 0.f;
#pragma unroll 4
    for (int k = 0; k < 80; ++k) {
      const float c = __uint_as_float(s2[k]);
      FINS5(M0, M1, M2, M3, M4, c);
    }
    const int row = row0 + wrg * 64 + rloc;
    uint32_t* dst = part + ((size_t)row * NCG + cb) * 5;
    dst[0] = __float_as_uint(M0);
    dst[1] = __float_as_uint(M1);
    dst[2] = __float_as_uint(M2);
    dst[3] = __float_as_uint(M3);
    dst[4] = __float_as_uint(M4);
  }
}

// ---------------- merge splits + RNG + exact fp32 loss (4 rows/block) ----------------
__global__ __launch_bounds__(256) void merge_loss_kernel(
    const float* __restrict__ x, const uint32_t* __restrict__ part,
    float* __restrict__ rowloss,
    uint32_t k1a, uint32_t k1b, uint32_t k2a, uint32_t k2b) {
  const int w = threadIdx.x >> 6, l = threadIdx.x & 63;
  const int i = blockIdx.x * 4 + w;
  __shared__ uint32_t cs[4][160];
  const uint32_t* src = part + (size_t)i * (NCG * 5);
  cs[w][l] = src[l];
  cs[w][64 + l] = src[64 + l];
  if (l < 32) cs[w][128 + l] = src[128 + l];
  __syncthreads();

  float T0 = 0.f, T1 = 0.f, T2 = 0.f, T3 = 0.f, T4 = 0.f;
  for (int rch = 0; rch < NCG; ++rch) {
    for (int q = 0; q < 5; ++q) {      // runs sorted desc -> early out (uniform)
      const float c = __uint_as_float(cs[w][rch * 5 + q]);
      if (c <= T4) break;
      FINS5(T0, T1, T2, T3, T4, c);
    }
  }

  // RNG: coin = uniform(k1) < 0.5 <=> MSB==0 ; randint(k2,0,5)
  const uint32_t cw = rng_word(tf2x32(k1a, k1b, 0u, (uint32_t)i));
  const bool coin = (cw >> 31) == 0u;
  const uint32_t hb = rng_word(tf2x32(k2a, k2b, 0u, (uint32_t)i));
  const uint32_t lb = rng_word(tf2x32(k2a, k2b, 0u, (uint32_t)(NB + i)));
  const int rr = (int)(((hb % 5u) + (lb % 5u)) % 5u);
  const int rank = coin ? 0 : rr;
  const float kch = (rank == 0) ? T0 : (rank == 1) ? T1 : (rank == 2) ? T2
                  : (rank == 3) ? T3 : T4;
  const int neg = 8191 - (int)(__float_as_uint(kch) & 8191u);

  // exact fp32 loss from raw x
  const float4 xa = *(const float4*)(x + (size_t)i * 512 + l * 4);
  const float4 xp = *(const float4*)(x + (size_t)i * 512 + 256 + l * 4);
  const float4 xn = *(const float4*)(x + (size_t)neg * 512 + 256 + l * 4);
  float sa = xa.x * xa.x + xa.y * xa.y + xa.z * xa.z + xa.w * xa.w;
  float sp = xp.x * xp.x + xp.y * xp.y + xp.z * xp.z + xp.w * xp.w;
  float sn = xn.x * xn.x + xn.y * xn.y + xn.z * xn.z + xn.w * xn.w;
#pragma unroll
  for (int off = 32; off; off >>= 1) {
    sa += __shfl_xor(sa, off); sp += __shfl_xor(sp, off); sn += __shfl_xor(sn, off);
  }
  const float na = fmaxf(sqrtf(sa), 1e-12f);
  const float np = fmaxf(sqrtf(sp), 1e-12f);
  const float nn = fmaxf(sqrtf(sn), 1e-12f);

  float pos = 0.f, ng = 0.f;
  {
    float av, pv, nv, dp, dn;
    av = xa.x / na; pv = xp.x / np; nv = xn.x / nn;
    dp = av - pv + EPSF; pos += dp * dp; dn = av - nv + EPSF; ng += dn * dn;
    av = xa.y / na; pv = xp.y / np; nv = xn.y / nn;
    dp = av - pv + EPSF; pos += dp * dp; dn = av - nv + EPSF; ng += dn * dn;
    av = xa.z / na; pv = xp.z / np; nv = xn.z / nn;
    dp = av - pv + EPSF; pos += dp * dp; dn = av - nv + EPSF; ng += dn * dn;
    av = xa.w / na; pv = xp.w / np; nv = xn.w / nn;
    dp = av - pv + EPSF; pos += dp * dp; dn = av - nv + EPSF; ng += dn * dn;
  }
#pragma unroll
  for (int off = 32; off; off >>= 1) {
    pos += __shfl_xor(pos, off); ng += __shfl_xor(ng, off);
  }
  if (l == 0) rowloss[i] = fmaxf(pos - ng, 0.0f);
}

// ---------------- deterministic mean ----------------
__global__ __launch_bounds__(256) void finalize_kernel(
    const float* __restrict__ rowloss, float* __restrict__ out) {
  __shared__ float s[256];
  const int t = threadIdx.x;
  float a = 0.f;
  for (int k = 0; k < NB / 256; ++k) a += rowloss[t + 256 * k];
  s[t] = a;
  __syncthreads();
  for (int h = 128; h; h >>= 1) {
    if (t < h) s[t] += s[t + h];
    __syncthreads();
  }
  if (t == 0) out[0] = s[0] / (float)NB;
}

extern "C" void kernel_launch(void* const* d_in, const int* in_sizes, int n_in,
                              void* d_out, int out_size, void* d_ws, size_t ws_size,
                              hipStream_t stream) {
  (void)in_sizes; (void)n_in; (void)out_size; (void)ws_size;
  const float* x = (const float*)d_in[0];
  float* out = (float*)d_out;
  char* ws = (char*)d_ws;

  __hip_bfloat16* abf = (__hip_bfloat16*)(ws);                            // 4 MB
  __hip_bfloat16* pbf = (__hip_bfloat16*)(ws + (size_t)4 * 1024 * 1024);  // 4 MB
  uint32_t* part = (uint32_t*)(ws + (size_t)8 * 1024 * 1024);             // 5.24 MB
  float* rowloss = (float*)(ws + (size_t)8 * 1024 * 1024 +
                            (size_t)NB * NCG * 5 * sizeof(uint32_t));     // 32 KB

  // JAX: kr = key(1); k1, k2 = split(kr)  (threefry partitionable)
  U2 c0 = tf2x32(0u, 1u, 0u, 0u);
  U2 c1 = tf2x32(0u, 1u, 0u, 1u);
  const uint32_t k1a = c0.x, k1b = c0.y;
  const uint32_t k2a = c1.x, k2b = c1.y;

  prep_kernel<<<NB / 4, 256, 0, stream>>>(x, abf, pbf);
  dist_topk_kernel<<<2048, 512, 0, stream>>>(abf, pbf, part);
  merge_loss_kernel<<<NB / 4, 256, 0, stream>>>(x, part, rowloss, k1a, k1b, k2a, k2b);
  finalize_kernel<<<1, 256, 0, stream>>>(rowloss, out);
}